// Round 8
// baseline (166.879 us; speedup 1.0000x reference)
//
#include <hip/hip_runtime.h>
#include <math.h>

#define TI 32          // i-rows per block
#define BLOCK 512      // 8 waves; each wave owns a 32-rank j-tile
#define DIM 16         // embedding dim
#define JC 256         // j-ranks per block = 8 waves * 32

typedef short bf16x8 __attribute__((ext_vector_type(8)));
typedef float f32x16 __attribute__((ext_vector_type(16)));

static __device__ __forceinline__ short f2bf(float f) {
    unsigned u = __builtin_bit_cast(unsigned, f);
    unsigned r = (u + 0x7FFFu + ((u >> 16) & 1u)) >> 16;   // RNE
    return (short)r;
}

// Counting sort of idx -> perm/skey sorted by key.
__global__ __launch_bounds__(1024) void sort_kernel(
    const int* __restrict__ idx, int B, int N,
    int* __restrict__ perm, int* __restrict__ skey)
{
    extern __shared__ int hist[];        // N ints
    __shared__ int wsum[16];
    const int tid = threadIdx.x;
    const int lane = tid & 63, wid = tid >> 6;
    for (int b = tid; b < N; b += 1024) hist[b] = 0;
    __syncthreads();
    for (int j = tid; j < B; j += 1024) atomicAdd(&hist[idx[j]], 1);
    __syncthreads();
    const int PB = (N + 1023) >> 10;
    int local[8];
    int sum = 0;
    #pragma unroll
    for (int q = 0; q < 8; ++q) {
        if (q < PB) {
            int b = tid * PB + q;
            local[q] = sum;
            if (b < N) sum += hist[b];
        }
    }
    int v = sum;
    for (int off = 1; off < 64; off <<= 1) {
        int u = __shfl_up(v, off);
        if (lane >= off) v += u;
    }
    if (lane == 63) wsum[wid] = v;
    __syncthreads();
    if (tid < 16) {
        int t = wsum[tid];
        for (int off = 1; off < 16; off <<= 1) {
            int u = __shfl_up(t, off);
            if (lane >= off) t += u;
        }
        wsum[tid] = t;
    }
    __syncthreads();
    int base = (wid == 0) ? 0 : wsum[wid - 1];
    int excl = base + v - sum;
    #pragma unroll
    for (int q = 0; q < 8; ++q) {
        if (q < PB) {
            int b = tid * PB + q;
            if (b < N) hist[b] = excl + local[q];
        }
    }
    __syncthreads();
    for (int j = tid; j < B; j += 1024) {
        int k = idx[j];
        int pos = atomicAdd(&hist[k], 1);
        perm[pos] = j;
        skey[pos] = k;
    }
}

// ws layout: [0]=s_wd [1]=s_w [2]=s_rep [3]=s_cnt (f64 atomics), [4]=ticket(u32)
__global__ __launch_bounds__(BLOCK, 4) void pair_kernel(
    const float* __restrict__ W, const int* __restrict__ skey,
    const int* __restrict__ perm, const float* __restrict__ z,
    int B, int N, int nblocks, double* __restrict__ ws, float* __restrict__ out)
{
    __shared__ double red[BLOCK / 64][4];

    const int tid  = threadIdx.x;
    const int wv   = tid >> 6;           // wave 0..7
    const int lane = tid & 63;
    const int half = lane >> 5;
    const int sub  = lane & 31;
    const int i0   = blockIdx.x * TI;
    const int jr0  = blockIdx.y * JC;

    const int irow  = i0 + sub;                  // A-fragment i-row (rank)
    const int jrank = jr0 + wv * 32 + sub;       // B-fragment j-rank
    const int kj    = skey[jrank];               // W column (sorted across lanes)

    // ---- direct W gather: 16 values per thread, coalesced via sorted kj ----
    float wg[16];
    #pragma unroll
    for (int r = 0; r < 16; ++r) {
        const int rowm = (r & 3) + 8 * (r >> 2) + 4 * half;   // C-fragment row
        const int skr  = skey[i0 + rowm];                      // L1-hot
        wg[r] = W[(size_t)skr * (size_t)N + (size_t)kj];
    }

    // ---- z reads via perm (z is L2-resident), norms on the fly ----
    float zi[DIM], zj[DIM];
    {
        const float4* zp = reinterpret_cast<const float4*>(z + (size_t)perm[irow] * DIM);
        #pragma unroll
        for (int q = 0; q < 4; ++q) {
            float4 vv = zp[q];
            zi[4*q+0]=vv.x; zi[4*q+1]=vv.y; zi[4*q+2]=vv.z; zi[4*q+3]=vv.w;
        }
    }
    {
        const float4* zp = reinterpret_cast<const float4*>(z + (size_t)perm[jrank] * DIM);
        #pragma unroll
        for (int q = 0; q < 4; ++q) {
            float4 vv = zp[q];
            zj[4*q+0]=vv.x; zj[4*q+1]=vv.y; zj[4*q+2]=vv.z; zj[4*q+3]=vv.w;
        }
    }
    float sqi = 0.f, sqj = 0.f;
    #pragma unroll
    for (int k = 0; k < DIM; ++k) { sqi = fmaf(zi[k], zi[k], sqi); sqj = fmaf(zj[k], zj[k], sqj); }
    const float ui = 1.0f / (1.0f - fminf(fmaxf(sqi, 0.f), 0.99999f)), vi = sqi * ui;
    const float uj = 1.0f / (1.0f - fminf(fmaxf(sqj, 0.f), 0.99999f)), vj = sqj * uj;

    // ---- MFMA fragments: x-1 = A1.B1 + A2.B2 (18-dim bilinear form) ----
    bf16x8 a1, b1, a2, b2;
    {
        float s = 2.0f * ui;
        #pragma unroll
        for (int e = 0; e < 8; ++e) a1[e] = f2bf(s * zi[8 * half + e]);
    }
    {
        float s = -2.0f * uj;
        #pragma unroll
        for (int e = 0; e < 8; ++e) b1[e] = f2bf(s * zj[8 * half + e]);
    }
    #pragma unroll
    for (int e = 0; e < 8; ++e) { a2[e] = 0; b2[e] = 0; }
    if (half == 0) {
        a2[0] = f2bf(2.0f * vi); a2[1] = f2bf(2.0f * ui);
        b2[0] = f2bf(uj);        b2[1] = f2bf(vj);
    }

    f32x16 acc = {};
    acc = __builtin_amdgcn_mfma_f32_32x32x16_bf16(a1, b1, acc, 0, 0, 0);
    acc = __builtin_amdgcn_mfma_f32_32x32x16_bf16(a2, b2, acc, 0, 0, 0);

    // ---- epilogue: 16 pairs per thread ----
    float a_wd = 0.f, a_w = 0.f, a_rep = 0.f, a_cnt = 0.f;
    #pragma unroll
    for (int r = 0; r < 16; ++r) {
        const int rowm = (r & 3) + 8 * (r >> 2) + 4 * half;
        float xm1 = fmaxf(acc[r], 0.0f);                     // sqd>=0 clamp
        float w = wg[r];
        float t = __builtin_amdgcn_sqrtf(fmaxf(xm1 * (xm1 + 2.0f), 1e-10f));
        float x = xm1 + 1.0f;
        float d = __logf(x + t);             // d = log(x+sqrt(x^2-1))
        bool diag = ((i0 + rowm) == jrank);
        if (diag) w = 0.0f;
        a_wd += w * d;
        a_w  += w;
        bool rep = (w == 0.0f) && !diag;     // exp(-d) = 1/(x+t) = x - t
        a_rep += rep ? (x - t) : 0.0f;
        a_cnt += rep ? 1.0f : 0.0f;
    }

    double vals[4] = { (double)a_wd, (double)a_w, (double)a_rep, (double)a_cnt };
    #pragma unroll
    for (int c = 0; c < 4; ++c) {
        double v = vals[c];
        for (int off = 32; off > 0; off >>= 1) v += __shfl_down(v, off);
        vals[c] = v;
    }
    if (lane == 0) {
        #pragma unroll
        for (int c = 0; c < 4; ++c) red[wv][c] = vals[c];
    }
    __syncthreads();
    if (tid == 0) {
        double tot[4] = {0.0, 0.0, 0.0, 0.0};
        for (int wgt = 0; wgt < BLOCK / 64; ++wgt)
            for (int c = 0; c < 4; ++c) tot[c] += red[wgt][c];
        #pragma unroll
        for (int c = 0; c < 4; ++c) atomicAdd(&ws[c], tot[c]);
        __threadfence();                                  // publish before ticket
        unsigned tk = atomicAdd((unsigned*)&ws[4], 1u);
        if (tk == (unsigned)(nblocks - 1)) {              // last block finishes
            double s0 = atomicAdd(&ws[0], 0.0);           // RMW read: sees all adds
            double s1 = atomicAdd(&ws[1], 0.0);
            double s2 = atomicAdd(&ws[2], 0.0);
            double s3 = atomicAdd(&ws[3], 0.0);
            out[0] = (float)(s0 / (s1 + 1e-8) + s2 / (s3 + 1e-8));
        }
    }
}

extern "C" void kernel_launch(void* const* d_in, const int* in_sizes, int n_in,
                              void* d_out, int out_size, void* d_ws, size_t ws_size,
                              hipStream_t stream)
{
    const float* z  = (const float*)d_in[0];
    const float* W  = (const float*)d_in[1];
    const int* idx  = (const int*)d_in[2];
    const int B = in_sizes[2];                       // 4096
    int N = 1;
    while ((long long)(N + 1) * (N + 1) <= (long long)in_sizes[1]) ++N;

    const int nblocks = (B / TI) * (B / JC);         // 128 * 16 = 2048

    // workspace: 4 f64 accumulators + ticket + perm/skey
    double* ws = (double*)d_ws;
    int* perm = (int*)(ws + 6);
    int* skey = perm + B;
    hipMemsetAsync(ws, 0, 6 * sizeof(double), stream);

    sort_kernel<<<1, 1024, (size_t)N * sizeof(int), stream>>>(idx, B, N, perm, skey);

    dim3 grid(B / TI, B / JC);
    pair_kernel<<<grid, BLOCK, 0, stream>>>(W, skey, perm, z, B, N, nblocks,
                                            ws, (float*)d_out);
}

// Round 9
// 79.303 us; speedup vs baseline: 2.1043x; 2.1043x over previous
//
#include <hip/hip_runtime.h>
#include <math.h>

#define TI 32          // i-rows per block
#define BLOCK 512      // 8 waves; each wave owns a 32-rank j-tile
#define DIM 16         // embedding dim
#define JC 256         // j-ranks per block = 8 waves * 32

typedef short bf16x8 __attribute__((ext_vector_type(8)));
typedef float f32x16 __attribute__((ext_vector_type(16)));

static __device__ __forceinline__ short f2bf(float f) {
    unsigned u = __builtin_bit_cast(unsigned, f);
    unsigned r = (u + 0x7FFFu + ((u >> 16) & 1u)) >> 16;   // RNE
    return (short)r;
}

// Counting sort of idx -> perm/skey sorted by key; then (same block) permute z
// into sorted order and precompute norms. One launch instead of two.
__global__ __launch_bounds__(1024) void sort_prep_kernel(
    const int* __restrict__ idx, const float* __restrict__ z, int B, int N,
    int* __restrict__ perm, int* __restrict__ skey,
    float* __restrict__ zs, float* __restrict__ sqs, float* __restrict__ ras)
{
    extern __shared__ int hist[];        // N ints
    __shared__ int wsum[16];
    const int tid = threadIdx.x;
    const int lane = tid & 63, wid = tid >> 6;
    for (int b = tid; b < N; b += 1024) hist[b] = 0;
    __syncthreads();
    for (int j = tid; j < B; j += 1024) atomicAdd(&hist[idx[j]], 1);
    __syncthreads();
    const int PB = (N + 1023) >> 10;
    int local[8];
    int sum = 0;
    #pragma unroll
    for (int q = 0; q < 8; ++q) {
        if (q < PB) {
            int b = tid * PB + q;
            local[q] = sum;
            if (b < N) sum += hist[b];
        }
    }
    int v = sum;
    for (int off = 1; off < 64; off <<= 1) {
        int u = __shfl_up(v, off);
        if (lane >= off) v += u;
    }
    if (lane == 63) wsum[wid] = v;
    __syncthreads();
    if (tid < 16) {
        int t = wsum[tid];
        for (int off = 1; off < 16; off <<= 1) {
            int u = __shfl_up(t, off);
            if (lane >= off) t += u;
        }
        wsum[tid] = t;
    }
    __syncthreads();
    int base = (wid == 0) ? 0 : wsum[wid - 1];
    int excl = base + v - sum;
    #pragma unroll
    for (int q = 0; q < 8; ++q) {
        if (q < PB) {
            int b = tid * PB + q;
            if (b < N) hist[b] = excl + local[q];
        }
    }
    __syncthreads();
    for (int j = tid; j < B; j += 1024) {
        int k = idx[j];
        int pos = atomicAdd(&hist[k], 1);
        perm[pos] = j;
        skey[pos] = k;
    }
    __syncthreads();                     // perm fully written (same block)

    // fused prep: zs[r] = z[perm[r]], norms
    for (int r = tid; r < B; r += 1024) {
        int p = perm[r];
        const float4* src = reinterpret_cast<const float4*>(z + (size_t)p * DIM);
        float4* dst = reinterpret_cast<float4*>(zs + (size_t)r * DIM);
        float s = 0.f;
        #pragma unroll
        for (int q = 0; q < 4; ++q) {
            float4 vv = src[q];
            dst[q] = vv;
            s = fmaf(vv.x, vv.x, s); s = fmaf(vv.y, vv.y, s);
            s = fmaf(vv.z, vv.z, s); s = fmaf(vv.w, vv.w, s);
        }
        sqs[r] = s;
        float sc = fminf(fmaxf(s, 0.f), 0.99999f);
        ras[r] = 1.0f / (1.0f - sc);
    }
}

__global__ __launch_bounds__(BLOCK, 4) void pair_kernel(
    const float* __restrict__ W, const int* __restrict__ skey,
    const float* __restrict__ zs, const float* __restrict__ sqs,
    const float* __restrict__ ras,
    int B, int N, double* __restrict__ partial)
{
    __shared__ double red[BLOCK / 64][4];
    __shared__ int skl[TI];

    const int tid  = threadIdx.x;
    const int wv   = tid >> 6;           // wave 0..7
    const int lane = tid & 63;
    const int half = lane >> 5;
    const int sub  = lane & 31;
    const int i0   = blockIdx.x * TI;
    const int jr0  = blockIdx.y * JC;

    if (tid < TI) skl[tid] = skey[i0 + tid];
    __syncthreads();

    const int irow  = i0 + sub;                  // A-fragment i-row
    const int jrank = jr0 + wv * 32 + sub;       // B-fragment j-rank
    const int kj    = skey[jrank];               // W column (sorted across lanes)

    // ---- direct W gather: 16 values per thread, coalesced via sorted kj ----
    float wg[16];
    #pragma unroll
    for (int r = 0; r < 16; ++r) {
        const int rowm = (r & 3) + 8 * (r >> 2) + 4 * half;   // C-fragment row
        wg[r] = W[(size_t)skl[rowm] * (size_t)N + (size_t)kj];
    }

    // ---- MFMA fragments: x-1 = A1.B1 + A2.B2 (18-dim bilinear form) ----
    const float ui = ras[irow],  vi = sqs[irow]  * ui;
    const float uj = ras[jrank], vj = sqs[jrank] * uj;
    bf16x8 a1, b1, a2, b2;
    {
        const float4* zp = reinterpret_cast<const float4*>(zs + (size_t)irow * DIM + 8 * half);
        float4 p0 = zp[0], p1 = zp[1];
        float s = 2.0f * ui;
        a1[0]=f2bf(s*p0.x); a1[1]=f2bf(s*p0.y); a1[2]=f2bf(s*p0.z); a1[3]=f2bf(s*p0.w);
        a1[4]=f2bf(s*p1.x); a1[5]=f2bf(s*p1.y); a1[6]=f2bf(s*p1.z); a1[7]=f2bf(s*p1.w);
    }
    {
        const float4* zp = reinterpret_cast<const float4*>(zs + (size_t)jrank * DIM + 8 * half);
        float4 p0 = zp[0], p1 = zp[1];
        float s = -2.0f * uj;
        b1[0]=f2bf(s*p0.x); b1[1]=f2bf(s*p0.y); b1[2]=f2bf(s*p0.z); b1[3]=f2bf(s*p0.w);
        b1[4]=f2bf(s*p1.x); b1[5]=f2bf(s*p1.y); b1[6]=f2bf(s*p1.z); b1[7]=f2bf(s*p1.w);
    }
    #pragma unroll
    for (int e = 0; e < 8; ++e) { a2[e] = 0; b2[e] = 0; }
    if (half == 0) {
        a2[0] = f2bf(2.0f * vi); a2[1] = f2bf(2.0f * ui);
        b2[0] = f2bf(uj);        b2[1] = f2bf(vj);
    }

    f32x16 acc = {};
    acc = __builtin_amdgcn_mfma_f32_32x32x16_bf16(a1, b1, acc, 0, 0, 0);
    acc = __builtin_amdgcn_mfma_f32_32x32x16_bf16(a2, b2, acc, 0, 0, 0);

    // ---- epilogue: 16 pairs per thread ----
    float a_wd = 0.f, a_w = 0.f, a_rep = 0.f, a_cnt = 0.f;
    #pragma unroll
    for (int r = 0; r < 16; ++r) {
        const int rowm = (r & 3) + 8 * (r >> 2) + 4 * half;
        float xm1 = fmaxf(acc[r], 0.0f);                     // sqd>=0 clamp
        float w = wg[r];
        float t = __builtin_amdgcn_sqrtf(fmaxf(xm1 * (xm1 + 2.0f), 1e-10f));
        float x = xm1 + 1.0f;
        float d = __logf(x + t);             // d = log(x+sqrt(x^2-1))
        bool diag = ((i0 + rowm) == jrank);
        if (diag) w = 0.0f;
        a_wd += w * d;
        a_w  += w;
        bool rep = (w == 0.0f) && !diag;     // exp(-d) = 1/(x+t) = x - t
        a_rep += rep ? (x - t) : 0.0f;
        a_cnt += rep ? 1.0f : 0.0f;
    }

    double vals[4] = { (double)a_wd, (double)a_w, (double)a_rep, (double)a_cnt };
    #pragma unroll
    for (int c = 0; c < 4; ++c) {
        double v = vals[c];
        for (int off = 32; off > 0; off >>= 1) v += __shfl_down(v, off);
        vals[c] = v;
    }
    if (lane == 0) {
        #pragma unroll
        for (int c = 0; c < 4; ++c) red[wv][c] = vals[c];
    }
    __syncthreads();
    if (tid == 0) {
        double tot[4] = {0.0, 0.0, 0.0, 0.0};
        for (int wgt = 0; wgt < BLOCK / 64; ++wgt)
            for (int c = 0; c < 4; ++c) tot[c] += red[wgt][c];
        size_t bid = (size_t)blockIdx.y * gridDim.x + blockIdx.x;
        #pragma unroll
        for (int c = 0; c < 4; ++c) partial[bid * 4 + c] = tot[c];
    }
}

__global__ __launch_bounds__(1024) void finish_kernel(
    const double* __restrict__ partial, int nblocks, float* __restrict__ out)
{
    __shared__ double red[16][4];
    const int tid = threadIdx.x, wid = tid >> 6, lane = tid & 63;
    double vals[4] = {0.0, 0.0, 0.0, 0.0};
    for (int b = tid; b < nblocks; b += 1024)
        for (int c = 0; c < 4; ++c) vals[c] += partial[(size_t)b * 4 + c];
    #pragma unroll
    for (int c = 0; c < 4; ++c) {
        double v = vals[c];
        for (int off = 32; off > 0; off >>= 1) v += __shfl_down(v, off);
        vals[c] = v;
    }
    if (lane == 0)
        for (int c = 0; c < 4; ++c) red[wid][c] = vals[c];
    __syncthreads();
    if (tid == 0) {
        double tot[4] = {0.0, 0.0, 0.0, 0.0};
        for (int wgt = 0; wgt < 16; ++wgt)
            for (int c = 0; c < 4; ++c) tot[c] += red[wgt][c];
        double la = tot[0] / (tot[1] + 1e-8);
        double lr = tot[2] / (tot[3] + 1e-8);
        out[0] = (float)(la + lr);
    }
}

extern "C" void kernel_launch(void* const* d_in, const int* in_sizes, int n_in,
                              void* d_out, int out_size, void* d_ws, size_t ws_size,
                              hipStream_t stream)
{
    const float* z  = (const float*)d_in[0];
    const float* W  = (const float*)d_in[1];
    const int* idx  = (const int*)d_in[2];
    const int B = in_sizes[2];                       // 4096
    int N = 1;
    while ((long long)(N + 1) * (N + 1) <= (long long)in_sizes[1]) ++N;

    const int nblocks = (B / TI) * (B / JC);         // 128 * 16 = 2048

    // workspace layout (16B-aligned sections)
    double* partial = (double*)d_ws;                 // nblocks*4 doubles
    int* perm     = (int*)(partial + (size_t)nblocks * 4);
    int* skey     = perm + B;
    float* zs     = (float*)(skey + B);              // B*DIM floats
    float* sqs    = zs + (size_t)B * DIM;
    float* ras    = sqs + B;

    sort_prep_kernel<<<1, 1024, (size_t)N * sizeof(int), stream>>>(
        idx, z, B, N, perm, skey, zs, sqs, ras);

    dim3 grid(B / TI, B / JC);
    pair_kernel<<<grid, BLOCK, 0, stream>>>(W, skey, zs, sqs, ras, B, N, partial);
    finish_kernel<<<1, 1024, 0, stream>>>(partial, nblocks, (float*)d_out);
}

// Round 10
// 77.029 us; speedup vs baseline: 2.1665x; 1.0295x over previous
//
#include <hip/hip_runtime.h>
#include <math.h>

#define TI 32          // i-rows per block
#define BLOCK 512      // 8 waves; each wave owns a 32-rank j-tile
#define DIM 16         // embedding dim
#define JC 256         // j-ranks per block = 8 waves * 32

typedef short bf16x8 __attribute__((ext_vector_type(8)));
typedef float f32x16 __attribute__((ext_vector_type(16)));

static __device__ __forceinline__ short f2bf(float f) {
    unsigned u = __builtin_bit_cast(unsigned, f);
    unsigned r = (u + 0x7FFFu + ((u >> 16) & 1u)) >> 16;   // RNE
    return (short)r;
}

// Counting sort of idx -> perm/skey sorted by key.
__global__ __launch_bounds__(1024) void sort_kernel(
    const int* __restrict__ idx, int B, int N,
    int* __restrict__ perm, int* __restrict__ skey)
{
    extern __shared__ int hist[];        // N ints
    __shared__ int wsum[16];
    const int tid = threadIdx.x;
    const int lane = tid & 63, wid = tid >> 6;
    for (int b = tid; b < N; b += 1024) hist[b] = 0;
    __syncthreads();
    for (int j = tid; j < B; j += 1024) atomicAdd(&hist[idx[j]], 1);
    __syncthreads();
    const int PB = (N + 1023) >> 10;
    int local[8];
    int sum = 0;
    #pragma unroll
    for (int q = 0; q < 8; ++q) {
        if (q < PB) {
            int b = tid * PB + q;
            local[q] = sum;
            if (b < N) sum += hist[b];
        }
    }
    int v = sum;
    for (int off = 1; off < 64; off <<= 1) {
        int u = __shfl_up(v, off);
        if (lane >= off) v += u;
    }
    if (lane == 63) wsum[wid] = v;
    __syncthreads();
    if (tid < 16) {
        int t = wsum[tid];
        for (int off = 1; off < 16; off <<= 1) {
            int u = __shfl_up(t, off);
            if (lane >= off) t += u;
        }
        wsum[tid] = t;
    }
    __syncthreads();
    int base = (wid == 0) ? 0 : wsum[wid - 1];
    int excl = base + v - sum;
    #pragma unroll
    for (int q = 0; q < 8; ++q) {
        if (q < PB) {
            int b = tid * PB + q;
            if (b < N) hist[b] = excl + local[q];
        }
    }
    __syncthreads();
    for (int j = tid; j < B; j += 1024) {
        int k = idx[j];
        int pos = atomicAdd(&hist[k], 1);
        perm[pos] = j;
        skey[pos] = k;
    }
}

__global__ __launch_bounds__(BLOCK, 8) void pair_kernel(
    const float* __restrict__ W, const int* __restrict__ skey,
    const int* __restrict__ perm, const float* __restrict__ z,
    int B, int N, double* __restrict__ partial)
{
    __shared__ double red[BLOCK / 64][4];

    const int tid  = threadIdx.x;
    const int wv   = tid >> 6;           // wave 0..7
    const int lane = tid & 63;
    const int half = lane >> 5;
    const int sub  = lane & 31;
    const int i0   = blockIdx.x * TI;
    const int jr0  = blockIdx.y * JC;

    const int irow  = i0 + sub;                  // A-fragment i-row (rank)
    const int jrank = jr0 + wv * 32 + sub;       // B-fragment j-rank
    const int kj    = skey[jrank];               // W column (sorted across lanes)

    // ---- direct W gather: 16 values per thread, coalesced via sorted kj ----
    float wg[16];
    #pragma unroll
    for (int r = 0; r < 16; ++r) {
        const int rowm = (r & 3) + 8 * (r >> 2) + 4 * half;   // C-fragment row
        const int skr  = skey[i0 + rowm];                      // L1-hot
        wg[r] = W[(size_t)skr * (size_t)N + (size_t)kj];
    }

    // ---- z reads via perm (z is L2/L3-resident), norms on the fly ----
    float zi[DIM], zj[DIM];
    {
        const float4* zp = reinterpret_cast<const float4*>(z + (size_t)perm[irow] * DIM);
        #pragma unroll
        for (int q = 0; q < 4; ++q) {
            float4 vv = zp[q];
            zi[4*q+0]=vv.x; zi[4*q+1]=vv.y; zi[4*q+2]=vv.z; zi[4*q+3]=vv.w;
        }
    }
    {
        const float4* zp = reinterpret_cast<const float4*>(z + (size_t)perm[jrank] * DIM);
        #pragma unroll
        for (int q = 0; q < 4; ++q) {
            float4 vv = zp[q];
            zj[4*q+0]=vv.x; zj[4*q+1]=vv.y; zj[4*q+2]=vv.z; zj[4*q+3]=vv.w;
        }
    }
    float sqi = 0.f, sqj = 0.f;
    #pragma unroll
    for (int k = 0; k < DIM; ++k) { sqi = fmaf(zi[k], zi[k], sqi); sqj = fmaf(zj[k], zj[k], sqj); }
    const float ui = 1.0f / (1.0f - fminf(fmaxf(sqi, 0.f), 0.99999f)), vi = sqi * ui;
    const float uj = 1.0f / (1.0f - fminf(fmaxf(sqj, 0.f), 0.99999f)), vj = sqj * uj;

    // ---- MFMA fragments: x-1 = A1.B1 + A2.B2 (18-dim bilinear form) ----
    bf16x8 a1, b1, a2, b2;
    {
        float s = 2.0f * ui;
        #pragma unroll
        for (int e = 0; e < 8; ++e) a1[e] = f2bf(s * zi[8 * half + e]);
    }
    {
        float s = -2.0f * uj;
        #pragma unroll
        for (int e = 0; e < 8; ++e) b1[e] = f2bf(s * zj[8 * half + e]);
    }
    #pragma unroll
    for (int e = 0; e < 8; ++e) { a2[e] = 0; b2[e] = 0; }
    if (half == 0) {
        a2[0] = f2bf(2.0f * vi); a2[1] = f2bf(2.0f * ui);
        b2[0] = f2bf(uj);        b2[1] = f2bf(vj);
    }

    f32x16 acc = {};
    acc = __builtin_amdgcn_mfma_f32_32x32x16_bf16(a1, b1, acc, 0, 0, 0);
    acc = __builtin_amdgcn_mfma_f32_32x32x16_bf16(a2, b2, acc, 0, 0, 0);

    // ---- epilogue: 16 pairs per thread ----
    float a_wd = 0.f, a_w = 0.f, a_rep = 0.f, a_cnt = 0.f;
    #pragma unroll
    for (int r = 0; r < 16; ++r) {
        const int rowm = (r & 3) + 8 * (r >> 2) + 4 * half;
        float xm1 = fmaxf(acc[r], 0.0f);                     // sqd>=0 clamp
        float w = wg[r];
        float t = __builtin_amdgcn_sqrtf(fmaxf(xm1 * (xm1 + 2.0f), 1e-10f));
        float x = xm1 + 1.0f;
        float d = __logf(x + t);             // d = log(x+sqrt(x^2-1))
        bool diag = ((i0 + rowm) == jrank);
        if (diag) w = 0.0f;
        a_wd += w * d;
        a_w  += w;
        bool rep = (w == 0.0f) && !diag;     // exp(-d) = 1/(x+t) = x - t
        a_rep += rep ? (x - t) : 0.0f;
        a_cnt += rep ? 1.0f : 0.0f;
    }

    double vals[4] = { (double)a_wd, (double)a_w, (double)a_rep, (double)a_cnt };
    #pragma unroll
    for (int c = 0; c < 4; ++c) {
        double v = vals[c];
        for (int off = 32; off > 0; off >>= 1) v += __shfl_down(v, off);
        vals[c] = v;
    }
    if (lane == 0) {
        #pragma unroll
        for (int c = 0; c < 4; ++c) red[wv][c] = vals[c];
    }
    __syncthreads();
    if (tid == 0) {
        double tot[4] = {0.0, 0.0, 0.0, 0.0};
        for (int wgt = 0; wgt < BLOCK / 64; ++wgt)
            for (int c = 0; c < 4; ++c) tot[c] += red[wgt][c];
        size_t bid = (size_t)blockIdx.y * gridDim.x + blockIdx.x;
        #pragma unroll
        for (int c = 0; c < 4; ++c) partial[bid * 4 + c] = tot[c];
    }
}

__global__ __launch_bounds__(1024) void finish_kernel(
    const double* __restrict__ partial, int nblocks, float* __restrict__ out)
{
    __shared__ double red[16][4];
    const int tid = threadIdx.x, wid = tid >> 6, lane = tid & 63;
    double vals[4] = {0.0, 0.0, 0.0, 0.0};
    for (int b = tid; b < nblocks; b += 1024)
        for (int c = 0; c < 4; ++c) vals[c] += partial[(size_t)b * 4 + c];
    #pragma unroll
    for (int c = 0; c < 4; ++c) {
        double v = vals[c];
        for (int off = 32; off > 0; off >>= 1) v += __shfl_down(v, off);
        vals[c] = v;
    }
    if (lane == 0)
        for (int c = 0; c < 4; ++c) red[wid][c] = vals[c];
    __syncthreads();
    if (tid == 0) {
        double tot[4] = {0.0, 0.0, 0.0, 0.0};
        for (int wgt = 0; wgt < 16; ++wgt)
            for (int c = 0; c < 4; ++c) tot[c] += red[wgt][c];
        double la = tot[0] / (tot[1] + 1e-8);
        double lr = tot[2] / (tot[3] + 1e-8);
        out[0] = (float)(la + lr);
    }
}

extern "C" void kernel_launch(void* const* d_in, const int* in_sizes, int n_in,
                              void* d_out, int out_size, void* d_ws, size_t ws_size,
                              hipStream_t stream)
{
    const float* z  = (const float*)d_in[0];
    const float* W  = (const float*)d_in[1];
    const int* idx  = (const int*)d_in[2];
    const int B = in_sizes[2];                       // 4096
    int N = 1;
    while ((long long)(N + 1) * (N + 1) <= (long long)in_sizes[1]) ++N;

    const int nblocks = (B / TI) * (B / JC);         // 128 * 16 = 2048

    // workspace layout
    double* partial = (double*)d_ws;                 // nblocks*4 doubles
    int* perm = (int*)(partial + (size_t)nblocks * 4);
    int* skey = perm + B;

    sort_kernel<<<1, 1024, (size_t)N * sizeof(int), stream>>>(idx, B, N, perm, skey);

    dim3 grid(B / TI, B / JC);
    pair_kernel<<<grid, BLOCK, 0, stream>>>(W, skey, perm, z, B, N, partial);
    finish_kernel<<<1, 1024, 0, stream>>>(partial, nblocks, (float*)d_out);
}

// Round 11
// 46.087 us; speedup vs baseline: 3.6210x; 1.6714x over previous
//
#include <hip/hip_runtime.h>
#include <math.h>

#define TI 32          // i-rows per block
#define BLOCK 512      // 8 waves
#define DIM 16         // embedding dim
#define JC 512         // j-ranks per block = 8 waves * 32 * 2 subtiles

typedef short bf16x8 __attribute__((ext_vector_type(8)));
typedef float f32x16 __attribute__((ext_vector_type(16)));

static __device__ __forceinline__ short f2bf(float f) {
    unsigned u = __builtin_bit_cast(unsigned, f);
    unsigned r = (u + 0x7FFFu + ((u >> 16) & 1u)) >> 16;   // RNE
    return (short)r;
}

// Counting sort of idx -> perm/skey sorted by key.
__global__ __launch_bounds__(1024) void sort_kernel(
    const int* __restrict__ idx, int B, int N,
    int* __restrict__ perm, int* __restrict__ skey)
{
    extern __shared__ int hist[];        // N ints
    __shared__ int wsum[16];
    const int tid = threadIdx.x;
    const int lane = tid & 63, wid = tid >> 6;
    for (int b = tid; b < N; b += 1024) hist[b] = 0;
    __syncthreads();
    for (int j = tid; j < B; j += 1024) atomicAdd(&hist[idx[j]], 1);
    __syncthreads();
    const int PB = (N + 1023) >> 10;
    int local[8];
    int sum = 0;
    #pragma unroll
    for (int q = 0; q < 8; ++q) {
        if (q < PB) {
            int b = tid * PB + q;
            local[q] = sum;
            if (b < N) sum += hist[b];
        }
    }
    int v = sum;
    for (int off = 1; off < 64; off <<= 1) {
        int u = __shfl_up(v, off);
        if (lane >= off) v += u;
    }
    if (lane == 63) wsum[wid] = v;
    __syncthreads();
    if (tid < 16) {
        int t = wsum[tid];
        for (int off = 1; off < 16; off <<= 1) {
            int u = __shfl_up(t, off);
            if (lane >= off) t += u;
        }
        wsum[tid] = t;
    }
    __syncthreads();
    int base = (wid == 0) ? 0 : wsum[wid - 1];
    int excl = base + v - sum;
    #pragma unroll
    for (int q = 0; q < 8; ++q) {
        if (q < PB) {
            int b = tid * PB + q;
            if (b < N) hist[b] = excl + local[q];
        }
    }
    __syncthreads();
    for (int j = tid; j < B; j += 1024) {
        int k = idx[j];
        int pos = atomicAdd(&hist[k], 1);
        perm[pos] = j;
        skey[pos] = k;
    }
}

// Permute z into sorted order; precompute raw sq-norm and 1/(1-clamped).
__global__ __launch_bounds__(256) void prep_kernel(
    const float* __restrict__ z, const int* __restrict__ perm, int B,
    float* __restrict__ zs, float* __restrict__ sqs, float* __restrict__ ras)
{
    int r = blockIdx.x * 256 + threadIdx.x;
    if (r >= B) return;
    int p = perm[r];
    const float4* src = reinterpret_cast<const float4*>(z + (size_t)p * DIM);
    float4* dst = reinterpret_cast<float4*>(zs + (size_t)r * DIM);
    float s = 0.f;
    #pragma unroll
    for (int q = 0; q < 4; ++q) {
        float4 v = src[q];
        dst[q] = v;
        s = fmaf(v.x, v.x, s); s = fmaf(v.y, v.y, s);
        s = fmaf(v.z, v.z, s); s = fmaf(v.w, v.w, s);
    }
    sqs[r] = s;                                  // raw (for sqdist)
    float sc = fminf(fmaxf(s, 0.f), 0.99999f);   // clamped (for alpha)
    ras[r] = 1.0f / (1.0f - sc);
}

__global__ __launch_bounds__(BLOCK, 4) void pair_kernel(
    const float* __restrict__ W, const int* __restrict__ skey,
    const float* __restrict__ zs, const float* __restrict__ sqs,
    const float* __restrict__ ras,
    int B, int N, double* __restrict__ partial)
{
    __shared__ double red[BLOCK / 64][4];

    const int tid  = threadIdx.x;
    const int wv   = tid >> 6;           // wave 0..7
    const int lane = tid & 63;
    const int half = lane >> 5;
    const int sub  = lane & 31;
    const int i0   = blockIdx.x * TI;
    const int jr0  = blockIdx.y * JC;

    // ---- i-side fragments built ONCE, reused for both j-subtiles ----
    const int irow = i0 + sub;
    const float ui = ras[irow], vi = sqs[irow] * ui;
    bf16x8 a1, a2;
    {
        const float4* zp = reinterpret_cast<const float4*>(zs + (size_t)irow * DIM + 8 * half);
        float4 p0 = zp[0], p1 = zp[1];
        float s = 2.0f * ui;
        a1[0]=f2bf(s*p0.x); a1[1]=f2bf(s*p0.y); a1[2]=f2bf(s*p0.z); a1[3]=f2bf(s*p0.w);
        a1[4]=f2bf(s*p1.x); a1[5]=f2bf(s*p1.y); a1[6]=f2bf(s*p1.z); a1[7]=f2bf(s*p1.w);
    }
    #pragma unroll
    for (int e = 0; e < 8; ++e) a2[e] = 0;
    if (half == 0) { a2[0] = f2bf(2.0f * vi); a2[1] = f2bf(2.0f * ui); }

    float a_wd = 0.f, a_w = 0.f, a_rep = 0.f, a_cnt = 0.f;

    #pragma unroll
    for (int s = 0; s < 2; ++s) {
        const int jrank = jr0 + (s * 8 + wv) * 32 + sub;   // B-fragment j-rank
        const int kj    = skey[jrank];          // W column (sorted across lanes)

        // direct W gather: 16 values, coalesced via sorted kj
        float wg[16];
        #pragma unroll
        for (int r = 0; r < 16; ++r) {
            const int rowm = (r & 3) + 8 * (r >> 2) + 4 * half;  // C-fragment row
            const int skr  = skey[i0 + rowm];                    // L1-hot
            wg[r] = W[(size_t)skr * (size_t)N + (size_t)kj];
        }

        // j-side fragments
        const float uj = ras[jrank], vj = sqs[jrank] * uj;
        bf16x8 b1, b2;
        {
            const float4* zp = reinterpret_cast<const float4*>(zs + (size_t)jrank * DIM + 8 * half);
            float4 p0 = zp[0], p1 = zp[1];
            float sc = -2.0f * uj;
            b1[0]=f2bf(sc*p0.x); b1[1]=f2bf(sc*p0.y); b1[2]=f2bf(sc*p0.z); b1[3]=f2bf(sc*p0.w);
            b1[4]=f2bf(sc*p1.x); b1[5]=f2bf(sc*p1.y); b1[6]=f2bf(sc*p1.z); b1[7]=f2bf(sc*p1.w);
        }
        #pragma unroll
        for (int e = 0; e < 8; ++e) b2[e] = 0;
        if (half == 0) { b2[0] = f2bf(uj); b2[1] = f2bf(vj); }

        f32x16 acc = {};
        acc = __builtin_amdgcn_mfma_f32_32x32x16_bf16(a1, b1, acc, 0, 0, 0);
        acc = __builtin_amdgcn_mfma_f32_32x32x16_bf16(a2, b2, acc, 0, 0, 0);

        // epilogue: 16 pairs
        #pragma unroll
        for (int r = 0; r < 16; ++r) {
            const int rowm = (r & 3) + 8 * (r >> 2) + 4 * half;
            float xm1 = fmaxf(acc[r], 0.0f);                 // sqd>=0 clamp
            float w = wg[r];
            float t = __builtin_amdgcn_sqrtf(fmaxf(xm1 * (xm1 + 2.0f), 1e-10f));
            float x = xm1 + 1.0f;
            float d = __logf(x + t);         // d = log(x+sqrt(x^2-1))
            bool diag = ((i0 + rowm) == jrank);
            if (diag) w = 0.0f;
            a_wd += w * d;
            a_w  += w;
            bool rep = (w == 0.0f) && !diag; // exp(-d) = 1/(x+t) = x - t
            a_rep += rep ? (x - t) : 0.0f;
            a_cnt += rep ? 1.0f : 0.0f;
        }
    }

    double vals[4] = { (double)a_wd, (double)a_w, (double)a_rep, (double)a_cnt };
    #pragma unroll
    for (int c = 0; c < 4; ++c) {
        double v = vals[c];
        for (int off = 32; off > 0; off >>= 1) v += __shfl_down(v, off);
        vals[c] = v;
    }
    if (lane == 0) {
        #pragma unroll
        for (int c = 0; c < 4; ++c) red[wv][c] = vals[c];
    }
    __syncthreads();
    if (tid == 0) {
        double tot[4] = {0.0, 0.0, 0.0, 0.0};
        for (int wgt = 0; wgt < BLOCK / 64; ++wgt)
            for (int c = 0; c < 4; ++c) tot[c] += red[wgt][c];
        size_t bid = (size_t)blockIdx.y * gridDim.x + blockIdx.x;
        #pragma unroll
        for (int c = 0; c < 4; ++c) partial[bid * 4 + c] = tot[c];
    }
}

__global__ __launch_bounds__(1024) void finish_kernel(
    const double* __restrict__ partial, int nblocks, float* __restrict__ out)
{
    __shared__ double red[16][4];
    const int tid = threadIdx.x, wid = tid >> 6, lane = tid & 63;
    double vals[4] = {0.0, 0.0, 0.0, 0.0};
    for (int b = tid; b < nblocks; b += 1024)
        for (int c = 0; c < 4; ++c) vals[c] += partial[(size_t)b * 4 + c];
    #pragma unroll
    for (int c = 0; c < 4; ++c) {
        double v = vals[c];
        for (int off = 32; off > 0; off >>= 1) v += __shfl_down(v, off);
        vals[c] = v;
    }
    if (lane == 0)
        for (int c = 0; c < 4; ++c) red[wid][c] = vals[c];
    __syncthreads();
    if (tid == 0) {
        double tot[4] = {0.0, 0.0, 0.0, 0.0};
        for (int wgt = 0; wgt < 16; ++wgt)
            for (int c = 0; c < 4; ++c) tot[c] += red[wgt][c];
        double la = tot[0] / (tot[1] + 1e-8);
        double lr = tot[2] / (tot[3] + 1e-8);
        out[0] = (float)(la + lr);
    }
}

extern "C" void kernel_launch(void* const* d_in, const int* in_sizes, int n_in,
                              void* d_out, int out_size, void* d_ws, size_t ws_size,
                              hipStream_t stream)
{
    const float* z  = (const float*)d_in[0];
    const float* W  = (const float*)d_in[1];
    const int* idx  = (const int*)d_in[2];
    const int B = in_sizes[2];                       // 4096
    int N = 1;
    while ((long long)(N + 1) * (N + 1) <= (long long)in_sizes[1]) ++N;

    const int nblocks = (B / TI) * (B / JC);         // 128 * 8 = 1024

    // workspace layout (16B-aligned sections)
    double* partial = (double*)d_ws;                 // nblocks*4 doubles
    int* perm = (int*)(partial + (size_t)nblocks * 4);
    int* skey = perm + B;
    float* zs = (float*)(skey + B);                  // B*DIM floats
    float* sqs = zs + (size_t)B * DIM;
    float* ras = sqs + B;

    sort_kernel<<<1, 1024, (size_t)N * sizeof(int), stream>>>(idx, B, N, perm, skey);
    prep_kernel<<<(B + 255) / 256, 256, 0, stream>>>(z, perm, B, zs, sqs, ras);

    dim3 grid(B / TI, B / JC);
    pair_kernel<<<grid, BLOCK, 0, stream>>>(W, skey, zs, sqs, ras, B, N, partial);
    finish_kernel<<<1, 1024, 0, stream>>>(partial, nblocks, (float*)d_out);
}

// Round 12
// 41.656 us; speedup vs baseline: 4.0062x; 1.1064x over previous
//
#include <hip/hip_runtime.h>
#include <math.h>

#define TI 32          // i-rows per block
#define BLOCK 512      // 8 waves; each wave owns a 32-rank j-tile
#define DIM 16         // embedding dim
#define JC 256         // j-ranks per block = 8 waves * 32

typedef short bf16x8 __attribute__((ext_vector_type(8)));
typedef float f32x16 __attribute__((ext_vector_type(16)));

static __device__ __forceinline__ short f2bf(float f) {
    unsigned u = __builtin_bit_cast(unsigned, f);
    unsigned r = (u + 0x7FFFu + ((u >> 16) & 1u)) >> 16;   // RNE
    return (short)r;
}

// Counting sort of idx -> perm/skey sorted by key; skeyN[r] = skey[r]*N (u32).
__global__ __launch_bounds__(1024) void sort_kernel(
    const int* __restrict__ idx, int B, int N,
    int* __restrict__ perm, int* __restrict__ skey, unsigned* __restrict__ skeyN)
{
    extern __shared__ int hist[];        // N ints
    __shared__ int wsum[16];
    const int tid = threadIdx.x;
    const int lane = tid & 63, wid = tid >> 6;
    for (int b = tid; b < N; b += 1024) hist[b] = 0;
    __syncthreads();
    for (int j = tid; j < B; j += 1024) atomicAdd(&hist[idx[j]], 1);
    __syncthreads();
    const int PB = (N + 1023) >> 10;
    int local[8];
    int sum = 0;
    #pragma unroll
    for (int q = 0; q < 8; ++q) {
        if (q < PB) {
            int b = tid * PB + q;
            local[q] = sum;
            if (b < N) sum += hist[b];
        }
    }
    int v = sum;
    for (int off = 1; off < 64; off <<= 1) {
        int u = __shfl_up(v, off);
        if (lane >= off) v += u;
    }
    if (lane == 63) wsum[wid] = v;
    __syncthreads();
    if (tid < 16) {
        int t = wsum[tid];
        for (int off = 1; off < 16; off <<= 1) {
            int u = __shfl_up(t, off);
            if (lane >= off) t += u;
        }
        wsum[tid] = t;
    }
    __syncthreads();
    int base = (wid == 0) ? 0 : wsum[wid - 1];
    int excl = base + v - sum;
    #pragma unroll
    for (int q = 0; q < 8; ++q) {
        if (q < PB) {
            int b = tid * PB + q;
            if (b < N) hist[b] = excl + local[q];
        }
    }
    __syncthreads();
    for (int j = tid; j < B; j += 1024) {
        int k = idx[j];
        int pos = atomicAdd(&hist[k], 1);
        perm[pos] = j;
        skey[pos] = k;
        skeyN[pos] = (unsigned)k * (unsigned)N;
    }
}

// Pre-bake MFMA operands: zb[r][k] = bf16(2*u_r*z_rk); pka = {bf16(2v),bf16(2u)};
// pkb = {bf16(u),bf16(v)}.  u = 1/(1-clamped |z|^2), v = |z|^2 * u (raw norm).
__global__ __launch_bounds__(256) void prep_kernel(
    const float* __restrict__ z, const int* __restrict__ perm, int B,
    unsigned short* __restrict__ zb, unsigned* __restrict__ pka,
    unsigned* __restrict__ pkb)
{
    int r = blockIdx.x * 256 + threadIdx.x;
    if (r >= B) return;
    int p = perm[r];
    const float4* src = reinterpret_cast<const float4*>(z + (size_t)p * DIM);
    float zr[DIM];
    float s = 0.f;
    #pragma unroll
    for (int q = 0; q < 4; ++q) {
        float4 vv = src[q];
        zr[4*q+0]=vv.x; zr[4*q+1]=vv.y; zr[4*q+2]=vv.z; zr[4*q+3]=vv.w;
        s = fmaf(vv.x, vv.x, s); s = fmaf(vv.y, vv.y, s);
        s = fmaf(vv.z, vv.z, s); s = fmaf(vv.w, vv.w, s);
    }
    float sc = fminf(fmaxf(s, 0.f), 0.99999f);
    float u = 1.0f / (1.0f - sc);
    float v = s * u;
    unsigned short h[DIM];
    float sa = 2.0f * u;
    #pragma unroll
    for (int k = 0; k < DIM; ++k) h[k] = (unsigned short)f2bf(sa * zr[k]);
    uint4* dst = reinterpret_cast<uint4*>(zb + (size_t)r * DIM);
    uint4 w0, w1;
    w0.x = h[0] | ((unsigned)h[1] << 16);  w0.y = h[2] | ((unsigned)h[3] << 16);
    w0.z = h[4] | ((unsigned)h[5] << 16);  w0.w = h[6] | ((unsigned)h[7] << 16);
    w1.x = h[8] | ((unsigned)h[9] << 16);  w1.y = h[10] | ((unsigned)h[11] << 16);
    w1.z = h[12] | ((unsigned)h[13] << 16); w1.w = h[14] | ((unsigned)h[15] << 16);
    dst[0] = w0; dst[1] = w1;
    pka[r] = (unsigned)(unsigned short)f2bf(2.0f * v)
           | ((unsigned)(unsigned short)f2bf(2.0f * u) << 16);
    pkb[r] = (unsigned)(unsigned short)f2bf(u)
           | ((unsigned)(unsigned short)f2bf(v) << 16);
}

__global__ __launch_bounds__(BLOCK, 4) void pair_kernel(
    const float* __restrict__ W, const int* __restrict__ skey,
    const unsigned* __restrict__ skeyN,
    const unsigned short* __restrict__ zb,
    const unsigned* __restrict__ pka, const unsigned* __restrict__ pkb,
    int B, int N, double* __restrict__ partial)
{
    __shared__ double red[BLOCK / 64][4];

    const int tid  = threadIdx.x;
    const int wv   = tid >> 6;           // wave 0..7
    const int lane = tid & 63;
    const int half = lane >> 5;
    const int sub  = lane & 31;
    const int i0   = blockIdx.x * TI;
    const int jr0  = blockIdx.y * JC;

    const int irow  = i0 + sub;                  // A-fragment i-row
    const int jrank = jr0 + wv * 32 + sub;       // B-fragment j-rank
    const unsigned kj = (unsigned)skey[jrank];   // W column (sorted across lanes)

    // ---- direct W gather: 16 values, coalesced via sorted kj; u32 addressing ----
    float wg[16];
    #pragma unroll
    for (int r = 0; r < 16; ++r) {
        const int rowm = (r & 3) + 8 * (r >> 2) + 4 * half;   // C-fragment row
        const unsigned off = skeyN[i0 + rowm] + kj;            // row*N + col (u32)
        wg[r] = W[(size_t)off];
    }

    // ---- fragments from pre-baked bf16 (no conversions) ----
    bf16x8 a1 = *reinterpret_cast<const bf16x8*>(zb + (size_t)irow * DIM + 8 * half);
    uint4 bv = *reinterpret_cast<const uint4*>(zb + (size_t)jrank * DIM + 8 * half);
    bv.x ^= 0x80008000u; bv.y ^= 0x80008000u;
    bv.z ^= 0x80008000u; bv.w ^= 0x80008000u;    // b1 = -zb[jrank] (exact bf16 neg)
    bf16x8 b1 = __builtin_bit_cast(bf16x8, bv);

    bf16x8 a2 = {}, b2 = {};
    if (half == 0) {
        unsigned pa = pka[irow], pb = pkb[jrank];
        a2[0] = (short)(pa & 0xffffu); a2[1] = (short)(pa >> 16);
        b2[0] = (short)(pb & 0xffffu); b2[1] = (short)(pb >> 16);
    }

    f32x16 acc = {};
    acc = __builtin_amdgcn_mfma_f32_32x32x16_bf16(a1, b1, acc, 0, 0, 0);
    acc = __builtin_amdgcn_mfma_f32_32x32x16_bf16(a2, b2, acc, 0, 0, 0);

    // ---- epilogue: 16 pairs per thread ----
    float a_wd = 0.f, a_w = 0.f, a_rep = 0.f, a_cnt = 0.f;
    #pragma unroll
    for (int r = 0; r < 16; ++r) {
        const int rowm = (r & 3) + 8 * (r >> 2) + 4 * half;
        float xm1 = fmaxf(acc[r], 0.0f);                     // sqd>=0 clamp
        float w = wg[r];
        float t = __builtin_amdgcn_sqrtf(fmaxf(xm1 * (xm1 + 2.0f), 1e-10f));
        float x = xm1 + 1.0f;
        float d = __logf(x + t);             // d = log(x+sqrt(x^2-1))
        bool diag = ((i0 + rowm) == jrank);
        if (diag) w = 0.0f;
        a_wd += w * d;
        a_w  += w;
        bool rep = (w == 0.0f) && !diag;     // exp(-d) = 1/(x+t) = x - t
        a_rep += rep ? (x - t) : 0.0f;
        a_cnt += rep ? 1.0f : 0.0f;
    }

    // ---- f32 wave reduce, f64 only at block level ----
    float vals[4] = { a_wd, a_w, a_rep, a_cnt };
    #pragma unroll
    for (int c = 0; c < 4; ++c) {
        float v = vals[c];
        for (int off = 32; off > 0; off >>= 1) v += __shfl_down(v, off);
        vals[c] = v;
    }
    if (lane == 0) {
        #pragma unroll
        for (int c = 0; c < 4; ++c) red[wv][c] = (double)vals[c];
    }
    __syncthreads();
    if (tid == 0) {
        double tot[4] = {0.0, 0.0, 0.0, 0.0};
        for (int wgt = 0; wgt < BLOCK / 64; ++wgt)
            for (int c = 0; c < 4; ++c) tot[c] += red[wgt][c];
        size_t bid = (size_t)blockIdx.y * gridDim.x + blockIdx.x;
        #pragma unroll
        for (int c = 0; c < 4; ++c) partial[bid * 4 + c] = tot[c];
    }
}

__global__ __launch_bounds__(1024) void finish_kernel(
    const double* __restrict__ partial, int nblocks, float* __restrict__ out)
{
    __shared__ double red[16][4];
    const int tid = threadIdx.x, wid = tid >> 6, lane = tid & 63;
    double vals[4] = {0.0, 0.0, 0.0, 0.0};
    for (int b = tid; b < nblocks; b += 1024)
        for (int c = 0; c < 4; ++c) vals[c] += partial[(size_t)b * 4 + c];
    #pragma unroll
    for (int c = 0; c < 4; ++c) {
        double v = vals[c];
        for (int off = 32; off > 0; off >>= 1) v += __shfl_down(v, off);
        vals[c] = v;
    }
    if (lane == 0)
        for (int c = 0; c < 4; ++c) red[wid][c] = vals[c];
    __syncthreads();
    if (tid == 0) {
        double tot[4] = {0.0, 0.0, 0.0, 0.0};
        for (int wgt = 0; wgt < 16; ++wgt)
            for (int c = 0; c < 4; ++c) tot[c] += red[wgt][c];
        double la = tot[0] / (tot[1] + 1e-8);
        double lr = tot[2] / (tot[3] + 1e-8);
        out[0] = (float)(la + lr);
    }
}

extern "C" void kernel_launch(void* const* d_in, const int* in_sizes, int n_in,
                              void* d_out, int out_size, void* d_ws, size_t ws_size,
                              hipStream_t stream)
{
    const float* z  = (const float*)d_in[0];
    const float* W  = (const float*)d_in[1];
    const int* idx  = (const int*)d_in[2];
    const int B = in_sizes[2];                       // 4096
    int N = 1;
    while ((long long)(N + 1) * (N + 1) <= (long long)in_sizes[1]) ++N;

    const int nblocks = (B / TI) * (B / JC);         // 128 * 16 = 2048

    // workspace layout (16B-aligned sections)
    double* partial = (double*)d_ws;                 // nblocks*4 doubles
    int* perm       = (int*)(partial + (size_t)nblocks * 4);
    int* skey       = perm + B;
    unsigned* skeyN = (unsigned*)(skey + B);
    unsigned* pka   = skeyN + B;
    unsigned* pkb   = pka + B;
    unsigned short* zbv = (unsigned short*)(pkb + B);  // B*DIM bf16

    sort_kernel<<<1, 1024, (size_t)N * sizeof(int), stream>>>(
        idx, B, N, perm, skey, skeyN);
    prep_kernel<<<(B + 255) / 256, 256, 0, stream>>>(z, perm, B, zbv, pka, pkb);

    dim3 grid(B / TI, B / JC);
    pair_kernel<<<grid, BLOCK, 0, stream>>>(W, skey, skeyN, zbv, pka, pkb,
                                            B, N, partial);
    finish_kernel<<<1, 1024, 0, stream>>>(partial, nblocks, (float*)d_out);
}

// Round 13
// 41.626 us; speedup vs baseline: 4.0091x; 1.0007x over previous
//
#include <hip/hip_runtime.h>
#include <math.h>

#define TI 32          // i-rows per block
#define BLOCK 512      // 8 waves; each wave owns a 32-rank j-tile
#define DIM 16         // embedding dim
#define JC 256         // j-ranks per block = 8 waves * 32

typedef short bf16x8 __attribute__((ext_vector_type(8)));
typedef float f32x16 __attribute__((ext_vector_type(16)));

static __device__ __forceinline__ short f2bf(float f) {
    unsigned u = __builtin_bit_cast(unsigned, f);
    unsigned r = (u + 0x7FFFu + ((u >> 16) & 1u)) >> 16;   // RNE
    return (short)r;
}

// Counting sort of idx -> perm/skey sorted by key; skeyN[r] = skey[r]*N (u32).
__global__ __launch_bounds__(1024) void sort_kernel(
    const int* __restrict__ idx, int B, int N,
    int* __restrict__ perm, int* __restrict__ skey, unsigned* __restrict__ skeyN)
{
    extern __shared__ int hist[];        // N ints
    __shared__ int wsum[16];
    const int tid = threadIdx.x;
    const int lane = tid & 63, wid = tid >> 6;
    for (int b = tid; b < N; b += 1024) hist[b] = 0;
    __syncthreads();
    for (int j = tid; j < B; j += 1024) atomicAdd(&hist[idx[j]], 1);
    __syncthreads();
    const int PB = (N + 1023) >> 10;
    int local[8];
    int sum = 0;
    #pragma unroll
    for (int q = 0; q < 8; ++q) {
        if (q < PB) {
            int b = tid * PB + q;
            local[q] = sum;
            if (b < N) sum += hist[b];
        }
    }
    int v = sum;
    for (int off = 1; off < 64; off <<= 1) {
        int u = __shfl_up(v, off);
        if (lane >= off) v += u;
    }
    if (lane == 63) wsum[wid] = v;
    __syncthreads();
    if (tid < 16) {
        int t = wsum[tid];
        for (int off = 1; off < 16; off <<= 1) {
            int u = __shfl_up(t, off);
            if (lane >= off) t += u;
        }
        wsum[tid] = t;
    }
    __syncthreads();
    int base = (wid == 0) ? 0 : wsum[wid - 1];
    int excl = base + v - sum;
    #pragma unroll
    for (int q = 0; q < 8; ++q) {
        if (q < PB) {
            int b = tid * PB + q;
            if (b < N) hist[b] = excl + local[q];
        }
    }
    __syncthreads();
    for (int j = tid; j < B; j += 1024) {
        int k = idx[j];
        int pos = atomicAdd(&hist[k], 1);
        perm[pos] = j;
        skey[pos] = k;
        skeyN[pos] = (unsigned)k * (unsigned)N;
    }
}

// Pre-bake MFMA operands: zb[r][k] = bf16(2*u_r*z_rk); pka = {bf16(2v),bf16(2u)};
// pkb = {bf16(u),bf16(v)}.  u = 1/(1-clamped |z|^2), v = |z|^2 * u (raw norm).
__global__ __launch_bounds__(256) void prep_kernel(
    const float* __restrict__ z, const int* __restrict__ perm, int B,
    unsigned short* __restrict__ zb, unsigned* __restrict__ pka,
    unsigned* __restrict__ pkb)
{
    int r = blockIdx.x * 256 + threadIdx.x;
    if (r >= B) return;
    int p = perm[r];
    const float4* src = reinterpret_cast<const float4*>(z + (size_t)p * DIM);
    float zr[DIM];
    float s = 0.f;
    #pragma unroll
    for (int q = 0; q < 4; ++q) {
        float4 vv = src[q];
        zr[4*q+0]=vv.x; zr[4*q+1]=vv.y; zr[4*q+2]=vv.z; zr[4*q+3]=vv.w;
        s = fmaf(vv.x, vv.x, s); s = fmaf(vv.y, vv.y, s);
        s = fmaf(vv.z, vv.z, s); s = fmaf(vv.w, vv.w, s);
    }
    float sc = fminf(fmaxf(s, 0.f), 0.99999f);
    float u = 1.0f / (1.0f - sc);
    float v = s * u;
    unsigned short h[DIM];
    float sa = 2.0f * u;
    #pragma unroll
    for (int k = 0; k < DIM; ++k) h[k] = (unsigned short)f2bf(sa * zr[k]);
    uint4* dst = reinterpret_cast<uint4*>(zb + (size_t)r * DIM);
    uint4 w0, w1;
    w0.x = h[0] | ((unsigned)h[1] << 16);  w0.y = h[2] | ((unsigned)h[3] << 16);
    w0.z = h[4] | ((unsigned)h[5] << 16);  w0.w = h[6] | ((unsigned)h[7] << 16);
    w1.x = h[8] | ((unsigned)h[9] << 16);  w1.y = h[10] | ((unsigned)h[11] << 16);
    w1.z = h[12] | ((unsigned)h[13] << 16); w1.w = h[14] | ((unsigned)h[15] << 16);
    dst[0] = w0; dst[1] = w1;
    pka[r] = (unsigned)(unsigned short)f2bf(2.0f * v)
           | ((unsigned)(unsigned short)f2bf(2.0f * u) << 16);
    pkb[r] = (unsigned)(unsigned short)f2bf(u)
           | ((unsigned)(unsigned short)f2bf(v) << 16);
}

// grid = (B/JC, B/TI): x = j-chunk (fast), y = i-tile. In-kernel chunked XCD
// swizzle: XCD k gets a contiguous run of i-tiles; within an i-tile the 16
// j-chunk blocks are temporally adjacent -> W rows stream quasi-sequentially.
__global__ __launch_bounds__(BLOCK, 4) void pair_kernel(
    const float* __restrict__ W, const int* __restrict__ skey,
    const unsigned* __restrict__ skeyN,
    const unsigned short* __restrict__ zb,
    const unsigned* __restrict__ pka, const unsigned* __restrict__ pkb,
    int B, int N, double* __restrict__ partial)
{
    __shared__ double red[BLOCK / 64][4];

    const int tid  = threadIdx.x;
    const int wv   = tid >> 6;           // wave 0..7
    const int lane = tid & 63;
    const int half = lane >> 5;
    const int sub  = lane & 31;

    const int nJT  = gridDim.x;                          // B/JC (16)
    const int nwg  = nJT * gridDim.y;                    // 2048 (divisible by 8)
    const int bid  = blockIdx.x + blockIdx.y * nJT;      // linear dispatch id
    const int cpx  = nwg >> 3;                           // blocks per XCD
    const int swz  = (bid & 7) * cpx + (bid >> 3);       // bijective chunked swizzle
    const int i0   = (swz / nJT) * TI;
    const int jr0  = (swz % nJT) * JC;

    const int irow  = i0 + sub;                  // A-fragment i-row
    const int jrank = jr0 + wv * 32 + sub;       // B-fragment j-rank
    const unsigned kj = (unsigned)skey[jrank];   // W column (sorted across lanes)

    // ---- direct W gather: 16 values, coalesced via sorted kj; u32 addressing ----
    float wg[16];
    #pragma unroll
    for (int r = 0; r < 16; ++r) {
        const int rowm = (r & 3) + 8 * (r >> 2) + 4 * half;   // C-fragment row
        const unsigned off = skeyN[i0 + rowm] + kj;            // row*N + col (u32)
        wg[r] = W[(size_t)off];
    }

    // ---- fragments from pre-baked bf16 (no conversions) ----
    bf16x8 a1 = *reinterpret_cast<const bf16x8*>(zb + (size_t)irow * DIM + 8 * half);
    uint4 bv = *reinterpret_cast<const uint4*>(zb + (size_t)jrank * DIM + 8 * half);
    bv.x ^= 0x80008000u; bv.y ^= 0x80008000u;
    bv.z ^= 0x80008000u; bv.w ^= 0x80008000u;    // b1 = -zb[jrank] (exact bf16 neg)
    bf16x8 b1 = __builtin_bit_cast(bf16x8, bv);

    bf16x8 a2 = {}, b2 = {};
    if (half == 0) {
        unsigned pa = pka[irow], pb = pkb[jrank];
        a2[0] = (short)(pa & 0xffffu); a2[1] = (short)(pa >> 16);
        b2[0] = (short)(pb & 0xffffu); b2[1] = (short)(pb >> 16);
    }

    f32x16 acc = {};
    acc = __builtin_amdgcn_mfma_f32_32x32x16_bf16(a1, b1, acc, 0, 0, 0);
    acc = __builtin_amdgcn_mfma_f32_32x32x16_bf16(a2, b2, acc, 0, 0, 0);

    // ---- epilogue: 16 pairs per thread ----
    float a_wd = 0.f, a_w = 0.f, a_rep = 0.f, a_cnt = 0.f;
    #pragma unroll
    for (int r = 0; r < 16; ++r) {
        const int rowm = (r & 3) + 8 * (r >> 2) + 4 * half;
        float xm1 = fmaxf(acc[r], 0.0f);                     // sqd>=0 clamp
        float w = wg[r];
        float t = __builtin_amdgcn_sqrtf(fmaxf(xm1 * (xm1 + 2.0f), 1e-10f));
        float x = xm1 + 1.0f;
        float d = __logf(x + t);             // d = log(x+sqrt(x^2-1))
        bool diag = ((i0 + rowm) == jrank);
        if (diag) w = 0.0f;
        a_wd += w * d;
        a_w  += w;
        bool rep = (w == 0.0f) && !diag;     // exp(-d) = 1/(x+t) = x - t
        a_rep += rep ? (x - t) : 0.0f;
        a_cnt += rep ? 1.0f : 0.0f;
    }

    // ---- f32 wave reduce, f64 only at block level ----
    float vals[4] = { a_wd, a_w, a_rep, a_cnt };
    #pragma unroll
    for (int c = 0; c < 4; ++c) {
        float v = vals[c];
        for (int off = 32; off > 0; off >>= 1) v += __shfl_down(v, off);
        vals[c] = v;
    }
    if (lane == 0) {
        #pragma unroll
        for (int c = 0; c < 4; ++c) red[wv][c] = (double)vals[c];
    }
    __syncthreads();
    if (tid == 0) {
        double tot[4] = {0.0, 0.0, 0.0, 0.0};
        for (int wgt = 0; wgt < BLOCK / 64; ++wgt)
            for (int c = 0; c < 4; ++c) tot[c] += red[wgt][c];
        #pragma unroll
        for (int c = 0; c < 4; ++c) partial[(size_t)bid * 4 + c] = tot[c];
    }
}

__global__ __launch_bounds__(1024) void finish_kernel(
    const double* __restrict__ partial, int nblocks, float* __restrict__ out)
{
    __shared__ double red[16][4];
    const int tid = threadIdx.x, wid = tid >> 6, lane = tid & 63;
    double vals[4] = {0.0, 0.0, 0.0, 0.0};
    for (int b = tid; b < nblocks; b += 1024)
        for (int c = 0; c < 4; ++c) vals[c] += partial[(size_t)b * 4 + c];
    #pragma unroll
    for (int c = 0; c < 4; ++c) {
        double v = vals[c];
        for (int off = 32; off > 0; off >>= 1) v += __shfl_down(v, off);
        vals[c] = v;
    }
    if (lane == 0)
        for (int c = 0; c < 4; ++c) red[wid][c] = vals[c];
    __syncthreads();
    if (tid == 0) {
        double tot[4] = {0.0, 0.0, 0.0, 0.0};
        for (int wgt = 0; wgt < 16; ++wgt)
            for (int c = 0; c < 4; ++c) tot[c] += red[wgt][c];
        double la = tot[0] / (tot[1] + 1e-8);
        double lr = tot[2] / (tot[3] + 1e-8);
        out[0] = (float)(la + lr);
    }
}

extern "C" void kernel_launch(void* const* d_in, const int* in_sizes, int n_in,
                              void* d_out, int out_size, void* d_ws, size_t ws_size,
                              hipStream_t stream)
{
    const float* z  = (const float*)d_in[0];
    const float* W  = (const float*)d_in[1];
    const int* idx  = (const int*)d_in[2];
    const int B = in_sizes[2];                       // 4096
    int N = 1;
    while ((long long)(N + 1) * (N + 1) <= (long long)in_sizes[1]) ++N;

    const int nblocks = (B / TI) * (B / JC);         // 128 * 16 = 2048

    // workspace layout (16B-aligned sections)
    double* partial = (double*)d_ws;                 // nblocks*4 doubles
    int* perm       = (int*)(partial + (size_t)nblocks * 4);
    int* skey       = perm + B;
    unsigned* skeyN = (unsigned*)(skey + B);
    unsigned* pka   = skeyN + B;
    unsigned* pkb   = pka + B;
    unsigned short* zbv = (unsigned short*)(pkb + B);  // B*DIM bf16

    sort_kernel<<<1, 1024, (size_t)N * sizeof(int), stream>>>(
        idx, B, N, perm, skey, skeyN);
    prep_kernel<<<(B + 255) / 256, 256, 0, stream>>>(z, perm, B, zbv, pka, pkb);

    dim3 grid(B / JC, B / TI);                       // x = j-chunk (fast), y = i-tile
    pair_kernel<<<grid, BLOCK, 0, stream>>>(W, skey, skeyN, zbv, pka, pkb,
                                            B, N, partial);
    finish_kernel<<<1, 1024, 0, stream>>>(partial, nblocks, (float*)d_out);
}